// Round 10
// baseline (225.668 us; speedup 1.0000x reference)
//
#include <hip/hip_runtime.h>
#include <math.h>

#define D_MODEL 768
#define NHEAD  12
#define HDIM   64
#define SEQ    1024
#define BATCH  8
#define MTOT   (BATCH*SEQ)   // 8192
#define QKV_LD 2304          // Q|K|V concatenated columns

typedef _Float16 f16;
typedef __attribute__((ext_vector_type(2))) __fp16 fp16x2;
typedef __attribute__((ext_vector_type(4))) _Float16 f16x4;
typedef __attribute__((ext_vector_type(8))) _Float16 f16x8;
typedef __attribute__((ext_vector_type(4))) float f32x4;
typedef __attribute__((ext_vector_type(16))) float f32x16;

union PFrag { unsigned u[4]; f16x8 v; };
union PackW { fp16x2 h; unsigned u; };

__device__ inline void gload_lds16(const void* g, void* l) {
    __builtin_amdgcn_global_load_lds(
        (const __attribute__((address_space(1))) void*)g,
        (__attribute__((address_space(3))) void*)l, 16, 0, 0);
}

// ---------------------------------------------------------------------------
// x (fp32) -> f16, vectorized 8/thread
// ---------------------------------------------------------------------------
__global__ __launch_bounds__(256) void cvt_f32_f16(
    const float* __restrict__ in, f16* __restrict__ out, int n8)
{
    const int i = blockIdx.x * 256 + threadIdx.x;
    if (i < n8) {
        const float4 a = *(const float4*)(in + (size_t)i * 8);
        const float4 b = *(const float4*)(in + (size_t)i * 8 + 4);
        f16x8 v;
        v[0] = (f16)a.x; v[1] = (f16)a.y; v[2] = (f16)a.z; v[3] = (f16)a.w;
        v[4] = (f16)b.x; v[5] = (f16)b.y; v[6] = (f16)b.z; v[7] = (f16)b.w;
        *(f16x8*)(out + (size_t)i * 8) = v;
    }
}

__global__ __launch_bounds__(256) void concat_bias(
    const float* __restrict__ bq, const float* __restrict__ bk,
    const float* __restrict__ bv, float* __restrict__ bqkv)
{
    const int i = blockIdx.x * 256 + threadIdx.x;
    if (i < QKV_LD)
        bqkv[i] = (i < 768) ? bq[i] : (i < 1536) ? bk[i - 768] : bv[i - 1536];
}

// ---------------------------------------------------------------------------
// All four W[768][768] fp32 -> W^T f16 in one launch (z selects matrix)
// ---------------------------------------------------------------------------
__global__ __launch_bounds__(256) void transpose_cvt_all(
    const float* __restrict__ Wq, const float* __restrict__ Wk,
    const float* __restrict__ Wv, const float* __restrict__ Wo,
    f16* __restrict__ Wqkv_t, f16* __restrict__ Wo_t)
{
    const int z = blockIdx.z;
    const float* src = (z == 0) ? Wq : (z == 1) ? Wk : (z == 2) ? Wv : Wo;
    f16* dst = (z < 3) ? (Wqkv_t + (size_t)z * 768 * 768) : Wo_t;

    __shared__ f16 tile[64][72];
    const int t  = threadIdx.x;
    const int k0 = blockIdx.y * 64;
    const int n0 = blockIdx.x * 64;
    {
        const int r  = t >> 4;
        const int c4 = (t & 15) * 4;
        #pragma unroll
        for (int u = 0; u < 4; ++u) {
            const int row = r + u * 16;
            const float4 a = *(const float4*)&src[(size_t)(k0 + row) * 768 + n0 + c4];
            tile[row][c4 + 0] = (f16)a.x;
            tile[row][c4 + 1] = (f16)a.y;
            tile[row][c4 + 2] = (f16)a.z;
            tile[row][c4 + 3] = (f16)a.w;
        }
    }
    __syncthreads();
    {
        const int rn = t >> 3;
        const int ck = (t & 7) * 8;
        #pragma unroll
        for (int u = 0; u < 2; ++u) {
            const int n = rn + u * 32;
            f16x8 v;
            #pragma unroll
            for (int q = 0; q < 8; ++q) v[q] = tile[ck + q][n];
            *(f16x8*)&dst[(size_t)(n0 + n) * 768 + k0 + ck] = v;
        }
    }
}

// ---------------------------------------------------------------------------
// C[M][N] = A[M][K]f16 @ Bt[N][K]f16^T + bias.  128x128 tile, 4 waves,
// 64x64/wave. global_load_lds(16B) staging, add-rotate k-slot swizzle.
// 1D grid with XCD-contiguous chunk mapping (grid % 8 == 0).
// ---------------------------------------------------------------------------
template<typename OUT_T>
__global__ __launch_bounds__(256) void gemm_f16_tn(
    const f16* __restrict__ A, const f16* __restrict__ Bt,
    const float* __restrict__ bias, OUT_T* __restrict__ C,
    int M, int N, int K, int nb)
{
    __shared__ f16 As[128 * 32];
    __shared__ f16 Bs[128 * 32];

    const int t    = threadIdx.x;
    const int l    = t & 63;
    const int w    = t >> 6;
    const int l15  = l & 15;
    const int lg   = l >> 4;
    const int wrow = (w >> 1) * 64;
    const int wcol = (w & 1) * 64;

    const int orig = blockIdx.x;
    const int cpx  = gridDim.x >> 3;
    const int nid  = (orig & 7) * cpx + (orig >> 3);
    const int row0 = (nid / nb) * 128;
    const int col0 = (nid % nb) * 128;

    int src_row[2], src_koff[2], lds_off[2];
    #pragma unroll
    for (int i = 0; i < 2; ++i) {
        const int c = t + 256 * i;
        const int r = c >> 2;
        src_row[i]  = r;
        src_koff[i] = (((c & 3) - (r >> 1)) & 3) * 8;
        lds_off[i]  = c * 16;
    }

    int a_off[4], b_off[4];
    #pragma unroll
    for (int i = 0; i < 4; ++i) {
        const int ra = wrow + i * 16 + l15;
        a_off[i] = ra * 64 + (((lg + (ra >> 1)) & 3) * 16);
        const int rb = wcol + i * 16 + l15;
        b_off[i] = rb * 64 + (((lg + (rb >> 1)) & 3) * 16);
    }

    f32x4 acc[4][4];
    #pragma unroll
    for (int i = 0; i < 4; ++i)
        #pragma unroll
        for (int j = 0; j < 4; ++j)
            acc[i][j] = (f32x4){0.f, 0.f, 0.f, 0.f};

    const f16* Abase = A  + (size_t)row0 * K;
    const f16* Bbase = Bt + (size_t)col0 * K;

    for (int k0 = 0; k0 < K; k0 += 32) {
        #pragma unroll
        for (int i = 0; i < 2; ++i) {
            gload_lds16(Abase + (size_t)src_row[i] * K + k0 + src_koff[i],
                        (char*)As + lds_off[i]);
            gload_lds16(Bbase + (size_t)src_row[i] * K + k0 + src_koff[i],
                        (char*)Bs + lds_off[i]);
        }
        __syncthreads();

        f16x8 af[4], bf[4];
        #pragma unroll
        for (int i = 0; i < 4; ++i) {
            af[i] = *(const f16x8*)((const char*)As + a_off[i]);
            bf[i] = *(const f16x8*)((const char*)Bs + b_off[i]);
        }
        #pragma unroll
        for (int i = 0; i < 4; ++i)
            #pragma unroll
            for (int j = 0; j < 4; ++j)
                acc[i][j] = __builtin_amdgcn_mfma_f32_16x16x32_f16(
                    af[i], bf[j], acc[i][j], 0, 0, 0);
        __syncthreads();
    }

    #pragma unroll
    for (int j = 0; j < 4; ++j) {
        const int col = col0 + wcol + j * 16 + l15;
        const float bj = bias[col];
        #pragma unroll
        for (int i = 0; i < 4; ++i) {
            const int row = row0 + wrow + i * 16 + lg * 4;
            #pragma unroll
            for (int q = 0; q < 4; ++q)
                C[(size_t)(row + q) * N + col] = (OUT_T)(acc[i][j][q] + bj);
        }
    }
}

// ---------------------------------------------------------------------------
// Flash attention, f16, 32x32x16 MFMA, KV-SPLIT:
// block = 256 thr = 4 waves = 2 q-groups (g) x 2 kv-halves (sh).
// Wave (g,sh): q-rows qb*64+g*32..+32, kv tiles sh*8..sh*8+7 (KVB=64).
// Swapped QK^T (lane-local q=l&31), exp2 softmax + defer-max + TREE
// reductions, P packed in-register (cvt_pkrtz + shfl_xor32), K/V in
// XOR-swizzled per-stream LDS (single-buffered, 2 barriers/iter),
// reg-prefetch spanning compute (T14). Flash-exact merge of kv-halves
// via LDS at the end. grid = 1536 1D, XCD-contiguous. LDS 32KB.
// ---------------------------------------------------------------------------
#define RESCALE_THR 10.0f   // exp2 domain; P bounded by 2^10, safe in f16
#define QMAP(r, hh) (((r) & 3) + 8 * ((r) >> 2) + 4 * (hh))

__global__ __launch_bounds__(256, 4) void attn_f16(
    const f16* __restrict__ QKV, f16* __restrict__ O)
{
    __shared__ __align__(16) char smem[32768];
    // staging layout: Ks[s] at s*8192, Vt[s] at 16384 + s*8192  (64x64 f16 ea)

    const int t   = threadIdx.x;
    const int w   = t >> 6;
    const int l   = t & 63;
    const int l31 = l & 31;
    const int h   = l >> 5;
    const int g   = w >> 1;           // q-group
    const int sh  = w & 1;            // kv-half
    const int sl  = (l & 7) << 4;     // XOR key for row=l31/l (row&7)

    const int orig = blockIdx.x;                 // 0..1535
    const int s    = (orig & 7) * 192 + (orig >> 3);
    const int bh   = s >> 4;                     // 0..95
    const int qb   = s & 15;                     // 0..15
    const int b  = bh / NHEAD;
    const int hd = bh % NHEAD;
    const int q0 = qb * 64;

    const size_t rowbase = (size_t)b * SEQ;
    const int qcol = hd * HDIM;
    const int kcol = 768 + hd * HDIM;
    const int vcol = 1536 + hd * HDIM;

    char* Ksh = smem + sh * 8192;           // own K stream
    char* Vsh = smem + 16384 + sh * 8192;   // own V stream

    // ---- hoist Q fragments (B-operand: col=l31=q, k=h*8+j per 16-d chunk) --
    const f16 hsc = (f16)(0.125f * 1.4426950408889634f);
    f16x8 qf[4];
    #pragma unroll
    for (int dc = 0; dc < 4; ++dc) {
        f16x8 v = *(const f16x8*)(QKV
            + (rowbase + q0 + g * 32 + l31) * QKV_LD
            + qcol + dc * 16 + h * 8);
        #pragma unroll
        for (int j = 0; j < 8; ++j) v[j] *= hsc;
        qf[dc] = v;
    }

    f32x16 ctx[2];
    #pragma unroll
    for (int dt = 0; dt < 2; ++dt)
        #pragma unroll
        for (int r = 0; r < 16; ++r) ctx[dt][r] = 0.f;
    float mrun = -INFINITY;
    float lrun = 0.f;

    // ---- staging addresses (wave stages its own stream; 128 thr/stream) ----
    // K: row l, cols g*32..+32 (4x f16x8). V: 4k x 8d block per thread.
    const int kc0 = g * 32;
    const int vk0 = (l & 15) * 4;
    const int vd0 = (l >> 4) * 8 + g * 32;
    const f16* kptr = QKV + (rowbase + l)   * QKV_LD + kcol + kc0;
    const f16* vptr = QKV + (rowbase + vk0) * QKV_LD + vcol + vd0;
    const size_t step = (size_t)64 * QKV_LD;
    const size_t tb   = (size_t)(sh * 8) * step;   // own kv-half base

    f16x8 kr[4], vr[4];
    #pragma unroll
    for (int j = 0; j < 4; ++j) {
        kr[j] = *(const f16x8*)(kptr + tb + j * 8);
        vr[j] = *(const f16x8*)(vptr + tb + (size_t)j * QKV_LD);
    }

    // stage tile sh*8 + 0
    #pragma unroll
    for (int j = 0; j < 4; ++j)
        *(f16x8*)(Ksh + l * 128 + (((kc0 + j * 8) * 2) ^ sl)) = kr[j];
    #pragma unroll
    for (int dj = 0; dj < 8; ++dj) {
        f16x4 wt;
        #pragma unroll
        for (int i = 0; i < 4; ++i) wt[i] = vr[i][dj];
        *(f16x4*)(Vsh + (vd0 + dj) * 128
                     + ((vk0 * 2) ^ (((vd0 + dj) & 7) << 4))) = wt;
    }
    // prefetch tile sh*8 + 1
    #pragma unroll
    for (int j = 0; j < 4; ++j) {
        kr[j] = *(const f16x8*)(kptr + tb + step + j * 8);
        vr[j] = *(const f16x8*)(vptr + tb + step + (size_t)j * QKV_LD);
    }
    __syncthreads();

    for (int it = 0; it < 8; ++it) {
        // ---- S^T = K @ Q^T : 2 k-tiles of 32x32, contraction d=64 ----
        f32x16 sacc[2];
        __builtin_amdgcn_s_setprio(1);
        #pragma unroll
        for (int kk = 0; kk < 2; ++kk) {
            f32x16 a;
            #pragma unroll
            for (int r = 0; r < 16; ++r) a[r] = 0.f;
            #pragma unroll
            for (int dc = 0; dc < 4; ++dc) {
                const f16x8 ka = *(const f16x8*)(Ksh + (kk * 32 + l31) * 128
                                                     + ((dc * 32 + h * 16) ^ sl));
                a = __builtin_amdgcn_mfma_f32_32x32x16_f16(ka, qf[dc], a, 0, 0, 0);
            }
            sacc[kk] = a;
        }
        __builtin_amdgcn_s_setprio(0);

        // ---- softmax (exp2 domain, defer-max, tree reductions) ----
        {
            float tm[16];
            #pragma unroll
            for (int r = 0; r < 16; ++r)
                tm[r] = fmaxf(sacc[0][r], sacc[1][r]);
            #pragma unroll
            for (int off = 8; off >= 1; off >>= 1)
                #pragma unroll
                for (int r = 0; r < 8; ++r)
                    if (r < off) tm[r] = fmaxf(tm[r], tm[r + off]);
            float tmax = fmaxf(tm[0], __shfl_xor(tm[0], 32));

            if (__any(tmax > mrun + RESCALE_THR)) {
                const float mnew = fmaxf(mrun, tmax);
                const float corr = exp2f(mrun - mnew);
                mrun = mnew;
                lrun *= corr;
                #pragma unroll
                for (int r = 0; r < 16; ++r) {
                    const float cr = __shfl(corr, QMAP(r, h));
                    ctx[0][r] *= cr;
                    ctx[1][r] *= cr;
                }
            }

            float sm[16];
            #pragma unroll
            for (int kk = 0; kk < 2; ++kk)
                #pragma unroll
                for (int r = 0; r < 16; ++r)
                    sacc[kk][r] = exp2f(sacc[kk][r] - mrun);
            #pragma unroll
            for (int r = 0; r < 16; ++r)
                sm[r] = sacc[0][r] + sacc[1][r];
            #pragma unroll
            for (int off = 8; off >= 1; off >>= 1)
                #pragma unroll
                for (int r = 0; r < 8; ++r)
                    if (r < off) sm[r] += sm[r + off];
            lrun += sm[0] + __shfl_xor(sm[0], 32);
        }

        // ---- pack P to f16 dwords, redistribute across half-waves ----
        unsigned paw[4][4];
        #pragma unroll
        for (int kk = 0; kk < 2; ++kk) {
            unsigned dw[8];
            #pragma unroll
            for (int i = 0; i < 8; ++i) {
                PackW u;
                u.h = __builtin_amdgcn_cvt_pkrtz(sacc[kk][2 * i], sacc[kk][2 * i + 1]);
                dw[i] = u.u;
            }
            const unsigned t0 = (unsigned)__shfl_xor((int)(h ? dw[0] : dw[2]), 32);
            const unsigned t1 = (unsigned)__shfl_xor((int)(h ? dw[1] : dw[3]), 32);
            const unsigned t2 = (unsigned)__shfl_xor((int)(h ? dw[4] : dw[6]), 32);
            const unsigned t3 = (unsigned)__shfl_xor((int)(h ? dw[5] : dw[7]), 32);
            paw[2 * kk][0]     = h ? t0    : dw[0];
            paw[2 * kk][1]     = h ? t1    : dw[1];
            paw[2 * kk][2]     = h ? dw[2] : t0;
            paw[2 * kk][3]     = h ? dw[3] : t1;
            paw[2 * kk + 1][0] = h ? t2    : dw[4];
            paw[2 * kk + 1][1] = h ? t3    : dw[5];
            paw[2 * kk + 1][2] = h ? dw[6] : t2;
            paw[2 * kk + 1][3] = h ? dw[7] : t3;
        }

        // ---- ctx += P V : A in-register, B = Vt swizzled b128 ----
        __builtin_amdgcn_s_setprio(1);
        #pragma unroll
        for (int c = 0; c < 4; ++c) {
            PFrag pf;
            pf.u[0] = paw[c][0]; pf.u[1] = paw[c][1];
            pf.u[2] = paw[c][2]; pf.u[3] = paw[c][3];
            #pragma unroll
            for (int dt = 0; dt < 2; ++dt) {
                const f16x8 vb = *(const f16x8*)(Vsh + (dt * 32 + l31) * 128
                                                     + ((c * 32 + h * 16) ^ sl));
                ctx[dt] = __builtin_amdgcn_mfma_f32_32x32x16_f16(pf.v, vb, ctx[dt], 0, 0, 0);
            }
        }
        __builtin_amdgcn_s_setprio(0);

        __syncthreads();   // A: everyone done reading this iter's tiles

        if (it < 7) {
            // stage tile sh*8 + it + 1 from regs
            #pragma unroll
            for (int j = 0; j < 4; ++j)
                *(f16x8*)(Ksh + l * 128 + (((kc0 + j * 8) * 2) ^ sl)) = kr[j];
            #pragma unroll
            for (int dj = 0; dj < 8; ++dj) {
                f16x4 wt;
                #pragma unroll
                for (int i = 0; i < 4; ++i) wt[i] = vr[i][dj];
                *(f16x4*)(Vsh + (vd0 + dj) * 128
                             + ((vk0 * 2) ^ (((vd0 + dj) & 7) << 4))) = wt;
            }
            if (it < 6) {
                const size_t off = tb + (size_t)(it + 2) * step;
                #pragma unroll
                for (int j = 0; j < 4; ++j) {
                    kr[j] = *(const f16x8*)(kptr + off + j * 8);
                    vr[j] = *(const f16x8*)(vptr + off + (size_t)j * QKV_LD);
                }
            }
        }
        __syncthreads();   // B: staging done
    }

    // ---- merge the two kv-halves (flash-exact) ----
    // sh==1 publishes ctx (lane stride 144B, conflict-free b128) + (m,l)
    {
        float* cb = (float*)(smem + g * 9216 + l * 144);
        float2* mlb = (float2*)(smem + 18432);
        if (sh == 1) {
            #pragma unroll
            for (int dt = 0; dt < 2; ++dt)
                #pragma unroll
                for (int c = 0; c < 4; ++c) {
                    f32x4 v;
                    v[0] = ctx[dt][c * 4 + 0]; v[1] = ctx[dt][c * 4 + 1];
                    v[2] = ctx[dt][c * 4 + 2]; v[3] = ctx[dt][c * 4 + 3];
                    *(f32x4*)(cb + dt * 16 + c * 4) = v;
                }
            mlb[g * 64 + l] = make_float2(mrun, lrun);
        }
        __syncthreads();
        if (sh == 0) {
            const float2 ml = mlb[g * 64 + l];
            const float mN = fmaxf(mrun, ml.x);
            const float fa = exp2f(mrun - mN);
            const float fb = exp2f(ml.x - mN);
            lrun = lrun * fa + ml.y * fb;
            f32x16 cB[2];
            #pragma unroll
            for (int dt = 0; dt < 2; ++dt)
                #pragma unroll
                for (int c = 0; c < 4; ++c) {
                    const f32x4 v = *(const f32x4*)(cb + dt * 16 + c * 4);
                    cB[dt][c * 4 + 0] = v[0]; cB[dt][c * 4 + 1] = v[1];
                    cB[dt][c * 4 + 2] = v[2]; cB[dt][c * 4 + 3] = v[3];
                }
            #pragma unroll
            for (int r = 0; r < 16; ++r) {
                const int src = QMAP(r, h);
                const float faq = __shfl(fa, src);
                const float fbq = __shfl(fb, src);
                ctx[0][r] = ctx[0][r] * faq + cB[0][r] * fbq;
                ctx[1][r] = ctx[1][r] * faq + cB[1][r] * fbq;
            }

            // ---- normalize + store (sh==0 waves cover all 64 q-rows) ----
            const float inv = 1.0f / lrun;
            #pragma unroll
            for (int r = 0; r < 16; ++r) {
                const float iv = __shfl(inv, QMAP(r, h));
                const size_t row = rowbase + q0 + g * 32 + QMAP(r, h);
                O[row * D_MODEL + qcol + l31]      = (f16)(ctx[0][r] * iv);
                O[row * D_MODEL + qcol + 32 + l31] = (f16)(ctx[1][r] * iv);
            }
        }
    }
}

// ---------------------------------------------------------------------------
extern "C" void kernel_launch(void* const* d_in, const int* in_sizes, int n_in,
                              void* d_out, int out_size, void* d_ws, size_t ws_size,
                              hipStream_t stream) {
    const float* x  = (const float*)d_in[0];
    const float* Wq = (const float*)d_in[1];
    const float* bq = (const float*)d_in[2];
    const float* Wk = (const float*)d_in[3];
    const float* bk = (const float*)d_in[4];
    const float* Wv = (const float*)d_in[5];
    const float* bv = (const float*)d_in[6];
    const float* Wo = (const float*)d_in[7];
    const float* bo = (const float*)d_in[8];
    float* out = (float*)d_out;

    char* ws = (char*)d_ws;
    f16*   QKV     = (f16*)(ws);                                   // 37,748,736 B
    f16*   xh      = (f16*)(ws + 37748736);                        // 12,582,912
    f16*   ctxh    = (f16*)(ws + 37748736 + 12582912);             // 12,582,912
    f16*   Wqkv_t  = (f16*)(ws + 37748736 + 2 * 12582912);         // 3,538,944
    f16*   Wo_t    = (f16*)(ws + 37748736 + 2 * 12582912 + 3538944);       // 1,179,648
    float* bqkv    = (float*)(ws + 37748736 + 2 * 12582912 + 3538944 + 1179648);

    hipLaunchKernelGGL(cvt_f32_f16, dim3(MTOT * D_MODEL / 8 / 256), dim3(256), 0, stream,
                       x, xh, MTOT * D_MODEL / 8);
    hipLaunchKernelGGL(concat_bias, dim3(9), dim3(256), 0, stream, bq, bk, bv, bqkv);
    hipLaunchKernelGGL(transpose_cvt_all, dim3(12, 12, 4), dim3(256), 0, stream,
                       Wq, Wk, Wv, Wo, Wqkv_t, Wo_t);

    // fused QKV projection: grid 18*64 = 1152 (XCD-chunked inside kernel)
    hipLaunchKernelGGL((gemm_f16_tn<f16>), dim3((QKV_LD / 128) * (MTOT / 128)), dim3(256), 0, stream,
                       xh, Wqkv_t, bqkv, QKV, MTOT, QKV_LD, D_MODEL, QKV_LD / 128);

    hipLaunchKernelGGL(attn_f16, dim3((SEQ / 64) * BATCH * NHEAD), dim3(256), 0, stream,
                       QKV, ctxh);

    // output projection: grid 6*64 = 384
    hipLaunchKernelGGL((gemm_f16_tn<float>), dim3((D_MODEL / 128) * (MTOT / 128)), dim3(256), 0, stream,
                       ctxh, Wo_t, bo, out, MTOT, D_MODEL, D_MODEL, D_MODEL / 128);
}

// Round 11
// 152.520 us; speedup vs baseline: 1.4796x; 1.4796x over previous
//
#include <hip/hip_runtime.h>
#include <math.h>

#define D_MODEL 768
#define NHEAD  12
#define HDIM   64
#define SEQ    1024
#define BATCH  8
#define MTOT   (BATCH*SEQ)   // 8192
#define QKV_LD 2304          // Q|K|V concatenated columns

typedef _Float16 f16;
typedef __attribute__((ext_vector_type(2))) __fp16 fp16x2;
typedef __attribute__((ext_vector_type(4))) _Float16 f16x4;
typedef __attribute__((ext_vector_type(8))) _Float16 f16x8;
typedef __attribute__((ext_vector_type(4))) float f32x4;
typedef __attribute__((ext_vector_type(16))) float f32x16;

union PFrag { unsigned u[4]; f16x8 v; };
union PackW { fp16x2 h; unsigned u; };

__device__ inline void gload_lds16(const void* g, void* l) {
    __builtin_amdgcn_global_load_lds(
        (const __attribute__((address_space(1))) void*)g,
        (__attribute__((address_space(3))) void*)l, 16, 0, 0);
}

// ---------------------------------------------------------------------------
// x (fp32) -> f16, vectorized 8/thread
// ---------------------------------------------------------------------------
__global__ __launch_bounds__(256) void cvt_f32_f16(
    const float* __restrict__ in, f16* __restrict__ out, int n8)
{
    const int i = blockIdx.x * 256 + threadIdx.x;
    if (i < n8) {
        const float4 a = *(const float4*)(in + (size_t)i * 8);
        const float4 b = *(const float4*)(in + (size_t)i * 8 + 4);
        f16x8 v;
        v[0] = (f16)a.x; v[1] = (f16)a.y; v[2] = (f16)a.z; v[3] = (f16)a.w;
        v[4] = (f16)b.x; v[5] = (f16)b.y; v[6] = (f16)b.z; v[7] = (f16)b.w;
        *(f16x8*)(out + (size_t)i * 8) = v;
    }
}

__global__ __launch_bounds__(256) void concat_bias(
    const float* __restrict__ bq, const float* __restrict__ bk,
    const float* __restrict__ bv, float* __restrict__ bqkv)
{
    const int i = blockIdx.x * 256 + threadIdx.x;
    if (i < QKV_LD)
        bqkv[i] = (i < 768) ? bq[i] : (i < 1536) ? bk[i - 768] : bv[i - 1536];
}

// ---------------------------------------------------------------------------
// All four W[768][768] fp32 -> W^T f16 in one launch (z selects matrix)
// ---------------------------------------------------------------------------
__global__ __launch_bounds__(256) void transpose_cvt_all(
    const float* __restrict__ Wq, const float* __restrict__ Wk,
    const float* __restrict__ Wv, const float* __restrict__ Wo,
    f16* __restrict__ Wqkv_t, f16* __restrict__ Wo_t)
{
    const int z = blockIdx.z;
    const float* src = (z == 0) ? Wq : (z == 1) ? Wk : (z == 2) ? Wv : Wo;
    f16* dst = (z < 3) ? (Wqkv_t + (size_t)z * 768 * 768) : Wo_t;

    __shared__ f16 tile[64][72];
    const int t  = threadIdx.x;
    const int k0 = blockIdx.y * 64;
    const int n0 = blockIdx.x * 64;
    {
        const int r  = t >> 4;
        const int c4 = (t & 15) * 4;
        #pragma unroll
        for (int u = 0; u < 4; ++u) {
            const int row = r + u * 16;
            const float4 a = *(const float4*)&src[(size_t)(k0 + row) * 768 + n0 + c4];
            tile[row][c4 + 0] = (f16)a.x;
            tile[row][c4 + 1] = (f16)a.y;
            tile[row][c4 + 2] = (f16)a.z;
            tile[row][c4 + 3] = (f16)a.w;
        }
    }
    __syncthreads();
    {
        const int rn = t >> 3;
        const int ck = (t & 7) * 8;
        #pragma unroll
        for (int u = 0; u < 2; ++u) {
            const int n = rn + u * 32;
            f16x8 v;
            #pragma unroll
            for (int q = 0; q < 8; ++q) v[q] = tile[ck + q][n];
            *(f16x8*)&dst[(size_t)(n0 + n) * 768 + k0 + ck] = v;
        }
    }
}

// ---------------------------------------------------------------------------
// C[M][N] = A[M][K]f16 @ Bt[N][K]f16^T + bias.  128x128 tile, 4 waves,
// 64x64/wave. global_load_lds(16B) staging, add-rotate k-slot swizzle.
// 1D grid with XCD-contiguous chunk mapping (grid % 8 == 0).
// ---------------------------------------------------------------------------
template<typename OUT_T>
__global__ __launch_bounds__(256) void gemm_f16_tn(
    const f16* __restrict__ A, const f16* __restrict__ Bt,
    const float* __restrict__ bias, OUT_T* __restrict__ C,
    int M, int N, int K, int nb)
{
    __shared__ f16 As[128 * 32];
    __shared__ f16 Bs[128 * 32];

    const int t    = threadIdx.x;
    const int l    = t & 63;
    const int w    = t >> 6;
    const int l15  = l & 15;
    const int lg   = l >> 4;
    const int wrow = (w >> 1) * 64;
    const int wcol = (w & 1) * 64;

    const int orig = blockIdx.x;
    const int cpx  = gridDim.x >> 3;
    const int nid  = (orig & 7) * cpx + (orig >> 3);
    const int row0 = (nid / nb) * 128;
    const int col0 = (nid % nb) * 128;

    int src_row[2], src_koff[2], lds_off[2];
    #pragma unroll
    for (int i = 0; i < 2; ++i) {
        const int c = t + 256 * i;
        const int r = c >> 2;
        src_row[i]  = r;
        src_koff[i] = (((c & 3) - (r >> 1)) & 3) * 8;
        lds_off[i]  = c * 16;
    }

    int a_off[4], b_off[4];
    #pragma unroll
    for (int i = 0; i < 4; ++i) {
        const int ra = wrow + i * 16 + l15;
        a_off[i] = ra * 64 + (((lg + (ra >> 1)) & 3) * 16);
        const int rb = wcol + i * 16 + l15;
        b_off[i] = rb * 64 + (((lg + (rb >> 1)) & 3) * 16);
    }

    f32x4 acc[4][4];
    #pragma unroll
    for (int i = 0; i < 4; ++i)
        #pragma unroll
        for (int j = 0; j < 4; ++j)
            acc[i][j] = (f32x4){0.f, 0.f, 0.f, 0.f};

    const f16* Abase = A  + (size_t)row0 * K;
    const f16* Bbase = Bt + (size_t)col0 * K;

    for (int k0 = 0; k0 < K; k0 += 32) {
        #pragma unroll
        for (int i = 0; i < 2; ++i) {
            gload_lds16(Abase + (size_t)src_row[i] * K + k0 + src_koff[i],
                        (char*)As + lds_off[i]);
            gload_lds16(Bbase + (size_t)src_row[i] * K + k0 + src_koff[i],
                        (char*)Bs + lds_off[i]);
        }
        __syncthreads();

        f16x8 af[4], bf[4];
        #pragma unroll
        for (int i = 0; i < 4; ++i) {
            af[i] = *(const f16x8*)((const char*)As + a_off[i]);
            bf[i] = *(const f16x8*)((const char*)Bs + b_off[i]);
        }
        #pragma unroll
        for (int i = 0; i < 4; ++i)
            #pragma unroll
            for (int j = 0; j < 4; ++j)
                acc[i][j] = __builtin_amdgcn_mfma_f32_16x16x32_f16(
                    af[i], bf[j], acc[i][j], 0, 0, 0);
        __syncthreads();
    }

    #pragma unroll
    for (int j = 0; j < 4; ++j) {
        const int col = col0 + wcol + j * 16 + l15;
        const float bj = bias[col];
        #pragma unroll
        for (int i = 0; i < 4; ++i) {
            const int row = row0 + wrow + i * 16 + lg * 4;
            #pragma unroll
            for (int q = 0; q < 4; ++q)
                C[(size_t)(row + q) * N + col] = (OUT_T)(acc[i][j][q] + bj);
        }
    }
}

// ---------------------------------------------------------------------------
// Flash attention, f16, 32x32x16 MFMA, KV-SPLIT:
// block = 256 thr = 4 waves = 2 q-groups (g) x 2 kv-halves (sh).
// Wave (g,sh): q-rows qb*64+g*32..+32, kv tiles sh*8..sh*8+7 (KVB=64).
// Swapped QK^T (lane-local q=l&31), exp2 softmax + defer-max + tree
// reductions, P packed in-register (cvt_pkrtz + shfl_xor32), K/V in
// XOR-swizzled per-stream LDS (single-buffered, 2 barriers/iter),
// reg-prefetch spanning compute (T14). Flash-exact merge of kv-halves
// via LDS at the end (streamed, no cB register buffer).
// launch_bounds (256,3): VGPR cap 128 -> no spill (round-10 lesson:
// (256,4) forced 64 VGPR -> 275MB scratch traffic).
// grid = 1536 1D, XCD-contiguous. LDS 32KB.
// ---------------------------------------------------------------------------
#define RESCALE_THR 10.0f   // exp2 domain; P bounded by 2^10, safe in f16
#define QMAP(r, hh) (((r) & 3) + 8 * ((r) >> 2) + 4 * (hh))

__global__ __launch_bounds__(256, 3) void attn_f16(
    const f16* __restrict__ QKV, f16* __restrict__ O)
{
    __shared__ __align__(16) char smem[32768];
    // staging layout: Ks[s] at s*8192, Vt[s] at 16384 + s*8192  (64x64 f16 ea)

    const int t   = threadIdx.x;
    const int w   = t >> 6;
    const int l   = t & 63;
    const int l31 = l & 31;
    const int h   = l >> 5;
    const int g   = w >> 1;           // q-group
    const int sh  = w & 1;            // kv-half
    const int sl  = (l & 7) << 4;     // XOR key for row=l31/l (row&7)

    const int orig = blockIdx.x;                 // 0..1535
    const int s    = (orig & 7) * 192 + (orig >> 3);
    const int bh   = s >> 4;                     // 0..95
    const int qb   = s & 15;                     // 0..15
    const int b  = bh / NHEAD;
    const int hd = bh % NHEAD;
    const int q0 = qb * 64;

    const size_t rowbase = (size_t)b * SEQ;
    const int qcol = hd * HDIM;
    const int kcol = 768 + hd * HDIM;
    const int vcol = 1536 + hd * HDIM;

    char* Ksh = smem + sh * 8192;           // own K stream
    char* Vsh = smem + 16384 + sh * 8192;   // own V stream

    // ---- hoist Q fragments (B-operand: col=l31=q, k=h*8+j per 16-d chunk) --
    const f16 hsc = (f16)(0.125f * 1.4426950408889634f);
    f16x8 qf[4];
    #pragma unroll
    for (int dc = 0; dc < 4; ++dc) {
        f16x8 v = *(const f16x8*)(QKV
            + (rowbase + q0 + g * 32 + l31) * QKV_LD
            + qcol + dc * 16 + h * 8);
        #pragma unroll
        for (int j = 0; j < 8; ++j) v[j] *= hsc;
        qf[dc] = v;
    }

    f32x16 ctx[2];
    #pragma unroll
    for (int dt = 0; dt < 2; ++dt)
        #pragma unroll
        for (int r = 0; r < 16; ++r) ctx[dt][r] = 0.f;
    float mrun = -INFINITY;
    float lrun = 0.f;

    // ---- staging addresses (wave stages its own stream; 128 thr/stream) ----
    // K: row l, cols g*32..+32 (4x f16x8). V: 4k x 8d block per thread.
    const int kc0 = g * 32;
    const int vk0 = (l & 15) * 4;
    const int vd0 = (l >> 4) * 8 + g * 32;
    const f16* kptr = QKV + (rowbase + l)   * QKV_LD + kcol + kc0;
    const f16* vptr = QKV + (rowbase + vk0) * QKV_LD + vcol + vd0;
    const size_t step = (size_t)64 * QKV_LD;
    const size_t tb   = (size_t)(sh * 8) * step;   // own kv-half base

    f16x8 kr[4], vr[4];
    #pragma unroll
    for (int j = 0; j < 4; ++j) {
        kr[j] = *(const f16x8*)(kptr + tb + j * 8);
        vr[j] = *(const f16x8*)(vptr + tb + (size_t)j * QKV_LD);
    }

    // stage tile sh*8 + 0
    #pragma unroll
    for (int j = 0; j < 4; ++j)
        *(f16x8*)(Ksh + l * 128 + (((kc0 + j * 8) * 2) ^ sl)) = kr[j];
    #pragma unroll
    for (int dj = 0; dj < 8; ++dj) {
        f16x4 wt;
        #pragma unroll
        for (int i = 0; i < 4; ++i) wt[i] = vr[i][dj];
        *(f16x4*)(Vsh + (vd0 + dj) * 128
                     + ((vk0 * 2) ^ (((vd0 + dj) & 7) << 4))) = wt;
    }
    // prefetch tile sh*8 + 1
    #pragma unroll
    for (int j = 0; j < 4; ++j) {
        kr[j] = *(const f16x8*)(kptr + tb + step + j * 8);
        vr[j] = *(const f16x8*)(vptr + tb + step + (size_t)j * QKV_LD);
    }
    __syncthreads();

    for (int it = 0; it < 8; ++it) {
        // ---- S^T = K @ Q^T : 2 k-tiles of 32x32, contraction d=64 ----
        f32x16 sacc[2];
        __builtin_amdgcn_s_setprio(1);
        #pragma unroll
        for (int kk = 0; kk < 2; ++kk) {
            f32x16 a;
            #pragma unroll
            for (int r = 0; r < 16; ++r) a[r] = 0.f;
            #pragma unroll
            for (int dc = 0; dc < 4; ++dc) {
                const f16x8 ka = *(const f16x8*)(Ksh + (kk * 32 + l31) * 128
                                                     + ((dc * 32 + h * 16) ^ sl));
                a = __builtin_amdgcn_mfma_f32_32x32x16_f16(ka, qf[dc], a, 0, 0, 0);
            }
            sacc[kk] = a;
        }
        __builtin_amdgcn_s_setprio(0);

        // ---- softmax (exp2 domain, defer-max, tree reductions) ----
        {
            float tm[16];
            #pragma unroll
            for (int r = 0; r < 16; ++r)
                tm[r] = fmaxf(sacc[0][r], sacc[1][r]);
            #pragma unroll
            for (int off = 8; off >= 1; off >>= 1)
                #pragma unroll
                for (int r = 0; r < 8; ++r)
                    if (r < off) tm[r] = fmaxf(tm[r], tm[r + off]);
            float tmax = fmaxf(tm[0], __shfl_xor(tm[0], 32));

            if (__any(tmax > mrun + RESCALE_THR)) {
                const float mnew = fmaxf(mrun, tmax);
                const float corr = exp2f(mrun - mnew);
                mrun = mnew;
                lrun *= corr;
                #pragma unroll
                for (int r = 0; r < 16; ++r) {
                    const float cr = __shfl(corr, QMAP(r, h));
                    ctx[0][r] *= cr;
                    ctx[1][r] *= cr;
                }
            }

            float sm[16];
            #pragma unroll
            for (int kk = 0; kk < 2; ++kk)
                #pragma unroll
                for (int r = 0; r < 16; ++r)
                    sacc[kk][r] = exp2f(sacc[kk][r] - mrun);
            #pragma unroll
            for (int r = 0; r < 16; ++r)
                sm[r] = sacc[0][r] + sacc[1][r];
            #pragma unroll
            for (int off = 8; off >= 1; off >>= 1)
                #pragma unroll
                for (int r = 0; r < 8; ++r)
                    if (r < off) sm[r] += sm[r + off];
            lrun += sm[0] + __shfl_xor(sm[0], 32);
        }

        // ---- pack P to f16 dwords, redistribute across half-waves ----
        unsigned paw[4][4];
        #pragma unroll
        for (int kk = 0; kk < 2; ++kk) {
            unsigned dw[8];
            #pragma unroll
            for (int i = 0; i < 8; ++i) {
                PackW u;
                u.h = __builtin_amdgcn_cvt_pkrtz(sacc[kk][2 * i], sacc[kk][2 * i + 1]);
                dw[i] = u.u;
            }
            const unsigned t0 = (unsigned)__shfl_xor((int)(h ? dw[0] : dw[2]), 32);
            const unsigned t1 = (unsigned)__shfl_xor((int)(h ? dw[1] : dw[3]), 32);
            const unsigned t2 = (unsigned)__shfl_xor((int)(h ? dw[4] : dw[6]), 32);
            const unsigned t3 = (unsigned)__shfl_xor((int)(h ? dw[5] : dw[7]), 32);
            paw[2 * kk][0]     = h ? t0    : dw[0];
            paw[2 * kk][1]     = h ? t1    : dw[1];
            paw[2 * kk][2]     = h ? dw[2] : t0;
            paw[2 * kk][3]     = h ? dw[3] : t1;
            paw[2 * kk + 1][0] = h ? t2    : dw[4];
            paw[2 * kk + 1][1] = h ? t3    : dw[5];
            paw[2 * kk + 1][2] = h ? dw[6] : t2;
            paw[2 * kk + 1][3] = h ? dw[7] : t3;
        }

        // ---- ctx += P V : A in-register, B = Vt swizzled b128 ----
        __builtin_amdgcn_s_setprio(1);
        #pragma unroll
        for (int c = 0; c < 4; ++c) {
            PFrag pf;
            pf.u[0] = paw[c][0]; pf.u[1] = paw[c][1];
            pf.u[2] = paw[c][2]; pf.u[3] = paw[c][3];
            #pragma unroll
            for (int dt = 0; dt < 2; ++dt) {
                const f16x8 vb = *(const f16x8*)(Vsh + (dt * 32 + l31) * 128
                                                     + ((c * 32 + h * 16) ^ sl));
                ctx[dt] = __builtin_amdgcn_mfma_f32_32x32x16_f16(pf.v, vb, ctx[dt], 0, 0, 0);
            }
        }
        __builtin_amdgcn_s_setprio(0);

        __syncthreads();   // A: everyone done reading this iter's tiles

        if (it < 7) {
            // stage tile sh*8 + it + 1 from regs
            #pragma unroll
            for (int j = 0; j < 4; ++j)
                *(f16x8*)(Ksh + l * 128 + (((kc0 + j * 8) * 2) ^ sl)) = kr[j];
            #pragma unroll
            for (int dj = 0; dj < 8; ++dj) {
                f16x4 wt;
                #pragma unroll
                for (int i = 0; i < 4; ++i) wt[i] = vr[i][dj];
                *(f16x4*)(Vsh + (vd0 + dj) * 128
                             + ((vk0 * 2) ^ (((vd0 + dj) & 7) << 4))) = wt;
            }
            if (it < 6) {
                const size_t off = tb + (size_t)(it + 2) * step;
                #pragma unroll
                for (int j = 0; j < 4; ++j) {
                    kr[j] = *(const f16x8*)(kptr + off + j * 8);
                    vr[j] = *(const f16x8*)(vptr + off + (size_t)j * QKV_LD);
                }
            }
        }
        __syncthreads();   // B: staging done
    }

    // ---- merge the two kv-halves (flash-exact, streamed reads) ----
    // sh==1 publishes ctx (lane stride 144B, conflict-free b128) + (m,l)
    {
        float* cb = (float*)(smem + g * 9216 + l * 144);
        float2* mlb = (float2*)(smem + 18432);
        if (sh == 1) {
            #pragma unroll
            for (int dt = 0; dt < 2; ++dt)
                #pragma unroll
                for (int c = 0; c < 4; ++c) {
                    f32x4 v;
                    v[0] = ctx[dt][c * 4 + 0]; v[1] = ctx[dt][c * 4 + 1];
                    v[2] = ctx[dt][c * 4 + 2]; v[3] = ctx[dt][c * 4 + 3];
                    *(f32x4*)(cb + dt * 16 + c * 4) = v;
                }
            mlb[g * 64 + l] = make_float2(mrun, lrun);
        }
        __syncthreads();
        if (sh == 0) {
            const float2 ml = mlb[g * 64 + l];
            const float mN = fmaxf(mrun, ml.x);
            const float fa = exp2f(mrun - mN);
            const float fb = exp2f(ml.x - mN);
            lrun = lrun * fa + ml.y * fb;
            #pragma unroll
            for (int dt = 0; dt < 2; ++dt)
                #pragma unroll
                for (int c = 0; c < 4; ++c) {
                    const f32x4 v = *(const f32x4*)(cb + dt * 16 + c * 4);
                    #pragma unroll
                    for (int j = 0; j < 4; ++j) {
                        const int r = c * 4 + j;
                        const int src = QMAP(r, h);
                        const float faq = __shfl(fa, src);
                        const float fbq = __shfl(fb, src);
                        ctx[dt][r] = ctx[dt][r] * faq + v[j] * fbq;
                    }
                }

            // ---- normalize + store (sh==0 waves cover all 64 q-rows) ----
            const float inv = 1.0f / lrun;
            #pragma unroll
            for (int r = 0; r < 16; ++r) {
                const float iv = __shfl(inv, QMAP(r, h));
                const size_t row = rowbase + q0 + g * 32 + QMAP(r, h);
                O[row * D_MODEL + qcol + l31]      = (f16)(ctx[0][r] * iv);
                O[row * D_MODEL + qcol + 32 + l31] = (f16)(ctx[1][r] * iv);
            }
        }
    }
}

// ---------------------------------------------------------------------------
extern "C" void kernel_launch(void* const* d_in, const int* in_sizes, int n_in,
                              void* d_out, int out_size, void* d_ws, size_t ws_size,
                              hipStream_t stream) {
    const float* x  = (const float*)d_in[0];
    const float* Wq = (const float*)d_in[1];
    const float* bq = (const float*)d_in[2];
    const float* Wk = (const float*)d_in[3];
    const float* bk = (const float*)d_in[4];
    const float* Wv = (const float*)d_in[5];
    const float* bv = (const float*)d_in[6];
    const float* Wo = (const float*)d_in[7];
    const float* bo = (const float*)d_in[8];
    float* out = (float*)d_out;

    char* ws = (char*)d_ws;
    f16*   QKV     = (f16*)(ws);                                   // 37,748,736 B
    f16*   xh      = (f16*)(ws + 37748736);                        // 12,582,912
    f16*   ctxh    = (f16*)(ws + 37748736 + 12582912);             // 12,582,912
    f16*   Wqkv_t  = (f16*)(ws + 37748736 + 2 * 12582912);         // 3,538,944
    f16*   Wo_t    = (f16*)(ws + 37748736 + 2 * 12582912 + 3538944);       // 1,179,648
    float* bqkv    = (float*)(ws + 37748736 + 2 * 12582912 + 3538944 + 1179648);

    hipLaunchKernelGGL(cvt_f32_f16, dim3(MTOT * D_MODEL / 8 / 256), dim3(256), 0, stream,
                       x, xh, MTOT * D_MODEL / 8);
    hipLaunchKernelGGL(concat_bias, dim3(9), dim3(256), 0, stream, bq, bk, bv, bqkv);
    hipLaunchKernelGGL(transpose_cvt_all, dim3(12, 12, 4), dim3(256), 0, stream,
                       Wq, Wk, Wv, Wo, Wqkv_t, Wo_t);

    // fused QKV projection: grid 18*64 = 1152 (XCD-chunked inside kernel)
    hipLaunchKernelGGL((gemm_f16_tn<f16>), dim3((QKV_LD / 128) * (MTOT / 128)), dim3(256), 0, stream,
                       xh, Wqkv_t, bqkv, QKV, MTOT, QKV_LD, D_MODEL, QKV_LD / 128);

    hipLaunchKernelGGL(attn_f16, dim3((SEQ / 64) * BATCH * NHEAD), dim3(256), 0, stream,
                       QKV, ctxh);

    // output projection: grid 6*64 = 384
    hipLaunchKernelGGL((gemm_f16_tn<float>), dim3((D_MODEL / 128) * (MTOT / 128)), dim3(256), 0, stream,
                       ctxh, Wo_t, bo, out, MTOT, D_MODEL, D_MODEL, D_MODEL / 128);
}

// Round 12
// 139.657 us; speedup vs baseline: 1.6159x; 1.0921x over previous
//
#include <hip/hip_runtime.h>
#include <math.h>

#define D_MODEL 768
#define NHEAD  12
#define HDIM   64
#define SEQ    1024
#define BATCH  8
#define MTOT   (BATCH*SEQ)   // 8192
#define QKV_LD 2304          // Q|K|V concatenated columns

typedef _Float16 f16;
typedef __attribute__((ext_vector_type(2))) __fp16 fp16x2;
typedef __attribute__((ext_vector_type(4))) _Float16 f16x4;
typedef __attribute__((ext_vector_type(8))) _Float16 f16x8;
typedef __attribute__((ext_vector_type(4))) float f32x4;
typedef __attribute__((ext_vector_type(16))) float f32x16;

union PFrag { unsigned u[4]; f16x8 v; };
union PackW { fp16x2 h; unsigned u; };

__device__ inline void gload_lds16(const void* g, void* l) {
    __builtin_amdgcn_global_load_lds(
        (const __attribute__((address_space(1))) void*)g,
        (__attribute__((address_space(3))) void*)l, 16, 0, 0);
}

// ---------------------------------------------------------------------------
// x (fp32) -> f16 (8/thread), with bias concat fused into blocks 0..8
// ---------------------------------------------------------------------------
__global__ __launch_bounds__(256) void cvt_f32_f16_fused(
    const float* __restrict__ in, f16* __restrict__ out, int n8,
    const float* __restrict__ bq, const float* __restrict__ bk,
    const float* __restrict__ bv, float* __restrict__ bqkv)
{
    const int i = blockIdx.x * 256 + threadIdx.x;
    if (i < n8) {
        const float4 a = *(const float4*)(in + (size_t)i * 8);
        const float4 b = *(const float4*)(in + (size_t)i * 8 + 4);
        f16x8 v;
        v[0] = (f16)a.x; v[1] = (f16)a.y; v[2] = (f16)a.z; v[3] = (f16)a.w;
        v[4] = (f16)b.x; v[5] = (f16)b.y; v[6] = (f16)b.z; v[7] = (f16)b.w;
        *(f16x8*)(out + (size_t)i * 8) = v;
    }
    if (i < QKV_LD)
        bqkv[i] = (i < 768) ? bq[i] : (i < 1536) ? bk[i - 768] : bv[i - 1536];
}

// ---------------------------------------------------------------------------
// All four W[768][768] fp32 -> W^T f16 in one launch (z selects matrix)
// ---------------------------------------------------------------------------
__global__ __launch_bounds__(256) void transpose_cvt_all(
    const float* __restrict__ Wq, const float* __restrict__ Wk,
    const float* __restrict__ Wv, const float* __restrict__ Wo,
    f16* __restrict__ Wqkv_t, f16* __restrict__ Wo_t)
{
    const int z = blockIdx.z;
    const float* src = (z == 0) ? Wq : (z == 1) ? Wk : (z == 2) ? Wv : Wo;
    f16* dst = (z < 3) ? (Wqkv_t + (size_t)z * 768 * 768) : Wo_t;

    __shared__ f16 tile[64][72];
    const int t  = threadIdx.x;
    const int k0 = blockIdx.y * 64;
    const int n0 = blockIdx.x * 64;
    {
        const int r  = t >> 4;
        const int c4 = (t & 15) * 4;
        #pragma unroll
        for (int u = 0; u < 4; ++u) {
            const int row = r + u * 16;
            const float4 a = *(const float4*)&src[(size_t)(k0 + row) * 768 + n0 + c4];
            tile[row][c4 + 0] = (f16)a.x;
            tile[row][c4 + 1] = (f16)a.y;
            tile[row][c4 + 2] = (f16)a.z;
            tile[row][c4 + 3] = (f16)a.w;
        }
    }
    __syncthreads();
    {
        const int rn = t >> 3;
        const int ck = (t & 7) * 8;
        #pragma unroll
        for (int u = 0; u < 2; ++u) {
            const int n = rn + u * 32;
            f16x8 v;
            #pragma unroll
            for (int q = 0; q < 8; ++q) v[q] = tile[ck + q][n];
            *(f16x8*)&dst[(size_t)(n0 + n) * 768 + k0 + ck] = v;
        }
    }
}

// ---------------------------------------------------------------------------
// C[M][N] = A[M][K]f16 @ Bt[N][K]f16^T + bias.  128x128 tile, 4 waves,
// 64x64/wave, BK=64 (12 K-steps at K=768 -> half the barriers of BK=32).
// global_load_lds(16B) staging; 8-slot add-rotate k-chunk swizzle:
//   row r stores source k-chunk c at slot (c + (r>>1)) & 7  (LDS linear)
//   reader of (row, chunk c) reads slot (c + (row>>1)) & 7
// -> frag-read banks depend on slot only: 8 slots x 16B = 128B, 2-way free.
// 1D grid, XCD-contiguous chunk mapping (grid % 8 == 0).
// ---------------------------------------------------------------------------
template<typename OUT_T>
__global__ __launch_bounds__(256) void gemm_f16_tn(
    const f16* __restrict__ A, const f16* __restrict__ Bt,
    const float* __restrict__ bias, OUT_T* __restrict__ C,
    int M, int N, int K, int nb)
{
    __shared__ f16 As[128 * 64];
    __shared__ f16 Bs[128 * 64];

    const int t    = threadIdx.x;
    const int l15  = (t & 63) & 15;
    const int lg   = (t & 63) >> 4;
    const int w    = t >> 6;
    const int wrow = (w >> 1) * 64;
    const int wcol = (w & 1) * 64;

    const int orig = blockIdx.x;
    const int cpx  = gridDim.x >> 3;
    const int nid  = (orig & 7) * cpx + (orig >> 3);
    const int row0 = (nid / nb) * 128;
    const int col0 = (nid % nb) * 128;

    // staging: 1024 16B-chunks per tile, 4 per thread; chunk c -> row c>>3,
    // stored slot c&7 holds source k-chunk ((c&7) - (row>>1)) & 7
    int src_row[4], src_koff[4], lds_off[4];
    #pragma unroll
    for (int i = 0; i < 4; ++i) {
        const int c = t + 256 * i;
        const int r = c >> 3;
        src_row[i]  = r;
        src_koff[i] = ((((c & 7) - (r >> 1)) & 7)) * 8;
        lds_off[i]  = c * 16;
    }

    // fragment read byte-offsets: [i][sub]
    int a_off[4][2], b_off[4][2];
    #pragma unroll
    for (int i = 0; i < 4; ++i) {
        const int ra = wrow + i * 16 + l15;
        const int rb = wcol + i * 16 + l15;
        #pragma unroll
        for (int s = 0; s < 2; ++s) {
            a_off[i][s] = ra * 128 + (((s * 4 + lg + (ra >> 1)) & 7) * 16);
            b_off[i][s] = rb * 128 + (((s * 4 + lg + (rb >> 1)) & 7) * 16);
        }
    }

    f32x4 acc[4][4];
    #pragma unroll
    for (int i = 0; i < 4; ++i)
        #pragma unroll
        for (int j = 0; j < 4; ++j)
            acc[i][j] = (f32x4){0.f, 0.f, 0.f, 0.f};

    const f16* Abase = A  + (size_t)row0 * K;
    const f16* Bbase = Bt + (size_t)col0 * K;

    for (int k0 = 0; k0 < K; k0 += 64) {
        #pragma unroll
        for (int i = 0; i < 4; ++i) {
            gload_lds16(Abase + (size_t)src_row[i] * K + k0 + src_koff[i],
                        (char*)As + lds_off[i]);
            gload_lds16(Bbase + (size_t)src_row[i] * K + k0 + src_koff[i],
                        (char*)Bs + lds_off[i]);
        }
        __syncthreads();

        #pragma unroll
        for (int s = 0; s < 2; ++s) {
            f16x8 af[4], bf[4];
            #pragma unroll
            for (int i = 0; i < 4; ++i) {
                af[i] = *(const f16x8*)((const char*)As + a_off[i][s]);
                bf[i] = *(const f16x8*)((const char*)Bs + b_off[i][s]);
            }
            #pragma unroll
            for (int i = 0; i < 4; ++i)
                #pragma unroll
                for (int j = 0; j < 4; ++j)
                    acc[i][j] = __builtin_amdgcn_mfma_f32_16x16x32_f16(
                        af[i], bf[j], acc[i][j], 0, 0, 0);
        }
        __syncthreads();
    }

    #pragma unroll
    for (int j = 0; j < 4; ++j) {
        const int col = col0 + wcol + j * 16 + l15;
        const float bj = bias[col];
        #pragma unroll
        for (int i = 0; i < 4; ++i) {
            const int row = row0 + wrow + i * 16 + lg * 4;
            #pragma unroll
            for (int q = 0; q < 4; ++q)
                C[(size_t)(row + q) * N + col] = (OUT_T)(acc[i][j][q] + bj);
        }
    }
}

// ---------------------------------------------------------------------------
// Flash attention, f16, 32x32x16 MFMA (round-9 proven structure).
// QBLK=128 (32 q-rows/wave), KVB=64, swapped QK^T (lane-local q=l&31),
// exp2 softmax + defer-max, P packed in-register (cvt_pkrtz + shfl_xor32),
// K/V^T in XOR-swizzled LDS, double-buffered, 1 barrier/kt; stage-writes
// hoisted before the PV cluster (same barrier window, alias-free).
// grid = 768 1D, XCD-contiguous. LDS 32KB.
// ---------------------------------------------------------------------------
#define RESCALE_THR 10.0f   // exp2 domain; P bounded by 2^10, safe in f16
#define QMAP(r, hh) (((r) & 3) + 8 * ((r) >> 2) + 4 * (hh))

__global__ __launch_bounds__(256, 3) void attn_f16(
    const f16* __restrict__ QKV, f16* __restrict__ O)
{
    __shared__ f16 KsB[2][64 * 64];   // [k][d], swizzled
    __shared__ f16 VtB[2][64 * 64];   // [d][k], swizzled

    const int t   = threadIdx.x;
    const int w   = t >> 6;
    const int l   = t & 63;
    const int l31 = l & 31;
    const int h   = l >> 5;
    const int sl  = (l & 7) << 4;     // read/write XOR key (row&7)

    const int orig = blockIdx.x;                 // 0..767
    const int s    = (orig & 7) * 96 + (orig >> 3);
    const int bh   = s >> 3;                     // 0..95
    const int qb   = s & 7;                      // 0..7
    const int b  = bh / NHEAD;
    const int hd = bh % NHEAD;
    const int q0 = qb * 128;

    const size_t rowbase = (size_t)b * SEQ;
    const int qcol = hd * HDIM;
    const int kcol = 768 + hd * HDIM;
    const int vcol = 1536 + hd * HDIM;

    // ---- hoist Q fragments (B-operand: col=l31=q, k=h*8+j per 16-d chunk) --
    const f16 hsc = (f16)(0.125f * 1.4426950408889634f);
    f16x8 qf[4];
    #pragma unroll
    for (int dc = 0; dc < 4; ++dc) {
        f16x8 v = *(const f16x8*)(QKV
            + (rowbase + q0 + w * 32 + l31) * QKV_LD
            + qcol + dc * 16 + h * 8);
        #pragma unroll
        for (int j = 0; j < 8; ++j) v[j] *= hsc;
        qf[dc] = v;
    }

    f32x16 ctx[2];
    #pragma unroll
    for (int dt = 0; dt < 2; ++dt)
        #pragma unroll
        for (int r = 0; r < 16; ++r) ctx[dt][r] = 0.f;
    float mrun = -INFINITY;
    float lrun = 0.f;

    // ---- staging addresses ----
    const int cb  = w * 16;                 // K: row k=l, 16-d chunk
    const int vk0 = (l & 15) * 4;           // V: 4k x 4d block per thread
    const int vd0 = ((l >> 4) + 4 * w) * 4;
    const f16* kptr = QKV + (rowbase + l)   * QKV_LD + kcol + cb;
    const f16* vptr = QKV + (rowbase + vk0) * QKV_LD + vcol + vd0;
    const size_t step = (size_t)64 * QKV_LD;

    f16x8 kr0, kr1;
    f16x4 vr[4];
    kr0 = *(const f16x8*)(kptr);
    kr1 = *(const f16x8*)(kptr + 8);
    #pragma unroll
    for (int i = 0; i < 4; ++i)
        vr[i] = *(const f16x4*)(vptr + (size_t)i * QKV_LD);

    // stage tile 0 -> buf 0
    {
        char* Kd = (char*)KsB[0];
        char* Vd = (char*)VtB[0];
        *(f16x8*)(Kd + l * 128 + ((cb * 2)      ^ sl)) = kr0;
        *(f16x8*)(Kd + l * 128 + ((cb * 2 + 16) ^ sl)) = kr1;
        #pragma unroll
        for (int di = 0; di < 4; ++di) {
            f16x4 wt;
            #pragma unroll
            for (int i = 0; i < 4; ++i) wt[i] = vr[i][di];
            *(f16x4*)(Vd + (vd0 + di) * 128
                         + ((vk0 * 2) ^ (((vd0 + di) & 7) << 4))) = wt;
        }
    }
    kr0 = *(const f16x8*)(kptr + step);
    kr1 = *(const f16x8*)(kptr + step + 8);
    #pragma unroll
    for (int i = 0; i < 4; ++i)
        vr[i] = *(const f16x4*)(vptr + step + (size_t)i * QKV_LD);
    __syncthreads();

    for (int kt = 0; kt < SEQ / 64; ++kt) {
        const int p = kt & 1;
        const char* Kp = (const char*)KsB[p];
        const char* Vp = (const char*)VtB[p];

        // ---- S^T = K @ Q^T : 2 k-tiles of 32x32, contraction d=64 ----
        f32x16 sacc[2];
        __builtin_amdgcn_s_setprio(1);
        #pragma unroll
        for (int kk = 0; kk < 2; ++kk) {
            f32x16 a;
            #pragma unroll
            for (int r = 0; r < 16; ++r) a[r] = 0.f;
            #pragma unroll
            for (int dc = 0; dc < 4; ++dc) {
                const f16x8 ka = *(const f16x8*)(Kp + (kk * 32 + l31) * 128
                                                    + ((dc * 32 + h * 16) ^ sl));
                a = __builtin_amdgcn_mfma_f32_32x32x16_f16(ka, qf[dc], a, 0, 0, 0);
            }
            sacc[kk] = a;
        }
        __builtin_amdgcn_s_setprio(0);

        // ---- softmax (exp2 domain, scale pre-folded, defer-max) ----
        {
            float tmax = sacc[0][0];
            #pragma unroll
            for (int r = 1; r < 16; ++r) tmax = fmaxf(tmax, sacc[0][r]);
            #pragma unroll
            for (int r = 0; r < 16; ++r) tmax = fmaxf(tmax, sacc[1][r]);
            tmax = fmaxf(tmax, __shfl_xor(tmax, 32));

            if (__any(tmax > mrun + RESCALE_THR)) {
                const float mnew = fmaxf(mrun, tmax);
                const float corr = exp2f(mrun - mnew);
                mrun = mnew;
                lrun *= corr;
                #pragma unroll
                for (int r = 0; r < 16; ++r) {
                    const float cr = __shfl(corr, QMAP(r, h));
                    ctx[0][r] *= cr;
                    ctx[1][r] *= cr;
                }
            }

            float ps = 0.f;
            #pragma unroll
            for (int kk = 0; kk < 2; ++kk)
                #pragma unroll
                for (int r = 0; r < 16; ++r) {
                    const float pe = exp2f(sacc[kk][r] - mrun);
                    ps += pe;
                    sacc[kk][r] = pe;
                }
            ps += __shfl_xor(ps, 32);
            lrun += ps;
        }

        // ---- pack P to f16 dwords, redistribute across half-waves ----
        unsigned paw[4][4];
        #pragma unroll
        for (int kk = 0; kk < 2; ++kk) {
            unsigned dw[8];
            #pragma unroll
            for (int i = 0; i < 8; ++i) {
                PackW u;
                u.h = __builtin_amdgcn_cvt_pkrtz(sacc[kk][2 * i], sacc[kk][2 * i + 1]);
                dw[i] = u.u;
            }
            const unsigned t0 = (unsigned)__shfl_xor((int)(h ? dw[0] : dw[2]), 32);
            const unsigned t1 = (unsigned)__shfl_xor((int)(h ? dw[1] : dw[3]), 32);
            const unsigned t2 = (unsigned)__shfl_xor((int)(h ? dw[4] : dw[6]), 32);
            const unsigned t3 = (unsigned)__shfl_xor((int)(h ? dw[5] : dw[7]), 32);
            paw[2 * kk][0]     = h ? t0    : dw[0];
            paw[2 * kk][1]     = h ? t1    : dw[1];
            paw[2 * kk][2]     = h ? dw[2] : t0;
            paw[2 * kk][3]     = h ? dw[3] : t1;
            paw[2 * kk + 1][0] = h ? t2    : dw[4];
            paw[2 * kk + 1][1] = h ? t3    : dw[5];
            paw[2 * kk + 1][2] = h ? dw[6] : t2;
            paw[2 * kk + 1][3] = h ? dw[7] : t3;
        }

        // ---- stage tile kt+1 into buf p^1 (before PV: drains under MFMA);
        //      issue global loads for kt+2 ----
        if (kt < SEQ / 64 - 1) {
            char* Kd = (char*)KsB[p ^ 1];
            char* Vd = (char*)VtB[p ^ 1];
            *(f16x8*)(Kd + l * 128 + ((cb * 2)      ^ sl)) = kr0;
            *(f16x8*)(Kd + l * 128 + ((cb * 2 + 16) ^ sl)) = kr1;
            #pragma unroll
            for (int di = 0; di < 4; ++di) {
                f16x4 wt;
                #pragma unroll
                for (int i = 0; i < 4; ++i) wt[i] = vr[i][di];
                *(f16x4*)(Vd + (vd0 + di) * 128
                             + ((vk0 * 2) ^ (((vd0 + di) & 7) << 4))) = wt;
            }
            if (kt < SEQ / 64 - 2) {
                const f16* kp = kptr + (size_t)(kt + 2) * step;
                const f16* vp = vptr + (size_t)(kt + 2) * step;
                kr0 = *(const f16x8*)(kp);
                kr1 = *(const f16x8*)(kp + 8);
                #pragma unroll
                for (int i = 0; i < 4; ++i)
                    vr[i] = *(const f16x4*)(vp + (size_t)i * QKV_LD);
            }
        }

        // ---- ctx += P V : A in-register, B = Vt swizzled b128 ----
        __builtin_amdgcn_s_setprio(1);
        #pragma unroll
        for (int c = 0; c < 4; ++c) {
            PFrag pf;
            pf.u[0] = paw[c][0]; pf.u[1] = paw[c][1];
            pf.u[2] = paw[c][2]; pf.u[3] = paw[c][3];
            #pragma unroll
            for (int dt = 0; dt < 2; ++dt) {
                const f16x8 vb = *(const f16x8*)(Vp + (dt * 32 + l31) * 128
                                                    + ((c * 32 + h * 16) ^ sl));
                ctx[dt] = __builtin_amdgcn_mfma_f32_32x32x16_f16(pf.v, vb, ctx[dt], 0, 0, 0);
            }
        }
        __builtin_amdgcn_s_setprio(0);

        __syncthreads();
    }

    // ---- normalize + store f16 ctx: lane holds d = dt*32+l31, q = QMAP(r,h)
    {
        const float inv = 1.0f / lrun;
        #pragma unroll
        for (int r = 0; r < 16; ++r) {
            const float iv = __shfl(inv, QMAP(r, h));
            const size_t row = rowbase + q0 + w * 32 + QMAP(r, h);
            O[row * D_MODEL + qcol + l31]      = (f16)(ctx[0][r] * iv);
            O[row * D_MODEL + qcol + 32 + l31] = (f16)(ctx[1][r] * iv);
        }
    }
}

// ---------------------------------------------------------------------------
extern "C" void kernel_launch(void* const* d_in, const int* in_sizes, int n_in,
                              void* d_out, int out_size, void* d_ws, size_t ws_size,
                              hipStream_t stream) {
    const float* x  = (const float*)d_in[0];
    const float* Wq = (const float*)d_in[1];
    const float* bq = (const float*)d_in[2];
    const float* Wk = (const float*)d_in[3];
    const float* bk = (const float*)d_in[4];
    const float* Wv = (const float*)d_in[5];
    const float* bv = (const float*)d_in[6];
    const float* Wo = (const float*)d_in[7];
    const float* bo = (const float*)d_in[8];
    float* out = (float*)d_out;

    char* ws = (char*)d_ws;
    f16*   QKV     = (f16*)(ws);                                   // 37,748,736 B
    f16*   xh      = (f16*)(ws + 37748736);                        // 12,582,912
    f16*   ctxh    = (f16*)(ws + 37748736 + 12582912);             // 12,582,912
    f16*   Wqkv_t  = (f16*)(ws + 37748736 + 2 * 12582912);         // 3,538,944
    f16*   Wo_t    = (f16*)(ws + 37748736 + 2 * 12582912 + 3538944);       // 1,179,648
    float* bqkv    = (float*)(ws + 37748736 + 2 * 12582912 + 3538944 + 1179648);

    hipLaunchKernelGGL(cvt_f32_f16_fused, dim3(MTOT * D_MODEL / 8 / 256), dim3(256), 0, stream,
                       x, xh, MTOT * D_MODEL / 8, bq, bk, bv, bqkv);
    hipLaunchKernelGGL(transpose_cvt_all, dim3(12, 12, 4), dim3(256), 0, stream,
                       Wq, Wk, Wv, Wo, Wqkv_t, Wo_t);

    // fused QKV projection: grid 18*64 = 1152 (XCD-chunked inside kernel)
    hipLaunchKernelGGL((gemm_f16_tn<f16>), dim3((QKV_LD / 128) * (MTOT / 128)), dim3(256), 0, stream,
                       xh, Wqkv_t, bqkv, QKV, MTOT, QKV_LD, D_MODEL, QKV_LD / 128);

    hipLaunchKernelGGL(attn_f16, dim3((SEQ / 128) * BATCH * NHEAD), dim3(256), 0, stream,
                       QKV, ctxh);

    // output projection: grid 6*64 = 384
    hipLaunchKernelGGL((gemm_f16_tn<float>), dim3((D_MODEL / 128) * (MTOT / 128)), dim3(256), 0, stream,
                       ctxh, Wo_t, bo, out, MTOT, D_MODEL, D_MODEL, D_MODEL / 128);
}